// Round 3
// baseline (1100.844 us; speedup 1.0000x reference)
//
#include <hip/hip_runtime.h>
#include <math.h>

typedef __attribute__((ext_vector_type(8))) __bf16 bf16x8;
typedef __attribute__((ext_vector_type(4))) float f32x4;
typedef __attribute__((ext_vector_type(2))) float f32x2;

#define DEV __device__ __forceinline__

DEV unsigned short f2bf(float f) {
    unsigned int u = __builtin_bit_cast(unsigned int, f);
    u += 0x7FFFu + ((u >> 16) & 1u);
    return (unsigned short)(u >> 16);
}
DEV unsigned int pack2(float a, float b) {
    return (unsigned int)f2bf(a) | ((unsigned int)f2bf(b) << 16);
}
DEV float gelu_exact(float v) {
    return 0.5f * v * (1.0f + erff(v * 0.70710678118654752f));
}
DEV bf16x8 bf8_from2(unsigned int lo) {
    uint4 t;
    t.x = lo; t.y = 0u; t.z = 0u; t.w = 0u;
    return __builtin_bit_cast(bf16x8, t);
}

// ---------------------------------------------------------------------------
// small prep kernels
// ---------------------------------------------------------------------------
__global__ void cast_bf16_kernel(const float* __restrict__ src,
                                 unsigned short* __restrict__ dst, int n) {
    int i = blockIdx.x * 256 + threadIdx.x;
    if (i < n) dst[i] = f2bf(src[i]);
}

// FW1 (2048 x 514) -> bf16 [2048][512] (cols 0..511 only)
__global__ void cast_fw1_kernel(const float* __restrict__ src,
                                unsigned short* __restrict__ dst) {
    int i = blockIdx.x * 256 + threadIdx.x;
    if (i < 2048 * 512) {
        int row = i >> 9, k = i & 511;
        dst[i] = f2bf(src[row * 514 + k]);
    }
}

// FW1 cols 512/513 -> packed bf16 pairs [2048]
__global__ void cast_fwsc_kernel(const float* __restrict__ src,
                                 unsigned int* __restrict__ dst) {
    int i = blockIdx.x * 256 + threadIdx.x;
    if (i < 2048) dst[i] = pack2(src[i * 514 + 512], src[i * 514 + 513]);
}

// per-batch modulation: gb[b][0..255]=gamma, gb[b][256..511]=beta
__global__ void gb_kernel(const float* __restrict__ x,
                          const float* __restrict__ LW1, const float* __restrict__ Lb1,
                          const float* __restrict__ LW2, const float* __restrict__ Lb2,
                          float* __restrict__ gb) {
    __shared__ float t[512];
    int b = blockIdx.x, tid = threadIdx.x;
    float s0 = x[((size_t)b * 256 + 128) * 514 + 512];
    float s1 = x[((size_t)b * 256 + 128) * 514 + 513];
    for (int j = tid; j < 512; j += 256)
        t[j] = gelu_exact(LW1[j * 2] * s0 + LW1[j * 2 + 1] * s1 + Lb1[j]);
    __syncthreads();
    for (int i = tid; i < 512; i += 256) {
        float a = Lb2[i];
        const float* wr = LW2 + (size_t)i * 512;
        for (int j = 0; j < 512; ++j) a += wr[j] * t[j];
        gb[(size_t)b * 512 + i] = a;
    }
}

// sc passthrough columns 512,513 of output
__global__ void sc_copy_kernel(const float* __restrict__ x, float* __restrict__ out) {
    size_t idx = (size_t)blockIdx.x * 256 + threadIdx.x;  // token index b*256+p
    size_t off = idx * 514 + 512;
    *(f32x2*)(out + off) = *(const f32x2*)(x + off);
}

// ---------------------------------------------------------------------------
// mixer: one workgroup per (b,h). Chain of three 64x256 @ 256x256 GEMMs.
// (unchanged — not the current bottleneck)
// ---------------------------------------------------------------------------
#define MPAD 264

__global__ __launch_bounds__(256, 2) void mixer_kernel(
    const float* __restrict__ x, const float* __restrict__ bs,
    const float* __restrict__ Hb1, const float* __restrict__ Hb2,
    const unsigned short* __restrict__ Wsb,
    const unsigned short* __restrict__ HW1b,
    const unsigned short* __restrict__ HW2b,
    const float* __restrict__ gb,
    float* __restrict__ out) {
    __shared__ unsigned short XT[64 * MPAD];
    __shared__ unsigned short S[64 * MPAD];

    const int bid = blockIdx.x;
    const int b = bid >> 3;
    const int h = bid & 7;
    const int tid = threadIdx.x;
    const int lane = tid & 63;
    const int w = tid >> 6;
    const int l15 = lane & 15;
    const int l4 = lane >> 4;

    {
        const int c = lane;
        const float* xp = x + ((size_t)b * 256) * 514 + (size_t)h * 64 + c;
        for (int i = 0; i < 32; ++i) {
            int p = (i * 4 + w) * 2;
            float v0 = xp[(size_t)p * 514];
            float v1 = xp[(size_t)(p + 1) * 514];
            *(unsigned int*)&XT[c * MPAD + p] = pack2(v0, v1);
        }
    }
    __syncthreads();

    f32x4 acc[4][4];

    #pragma unroll
    for (int mt = 0; mt < 4; ++mt)
        #pragma unroll
        for (int nt = 0; nt < 4; ++nt) acc[mt][nt] = 0.f;
    for (int kc = 0; kc < 8; ++kc) {
        bf16x8 bfr[4];
        #pragma unroll
        for (int nt = 0; nt < 4; ++nt) {
            int o = w * 64 + nt * 16 + l15;
            bfr[nt] = *(const bf16x8*)(Wsb + (size_t)o * 256 + kc * 32 + l4 * 8);
        }
        #pragma unroll
        for (int mt = 0; mt < 4; ++mt) {
            bf16x8 afr = *(const bf16x8*)&XT[(mt * 16 + l15) * MPAD + kc * 32 + l4 * 8];
            #pragma unroll
            for (int nt = 0; nt < 4; ++nt)
                acc[mt][nt] = __builtin_amdgcn_mfma_f32_16x16x32_bf16(afr, bfr[nt], acc[mt][nt], 0, 0, 0);
        }
    }
    #pragma unroll
    for (int nt = 0; nt < 4; ++nt) {
        int o = w * 64 + nt * 16 + l15;
        float bsv = bs[o];
        float g = gb[(size_t)b * 512 + o];
        float be = gb[(size_t)b * 512 + 256 + o];
        #pragma unroll
        for (int mt = 0; mt < 4; ++mt)
            #pragma unroll
            for (int r = 0; r < 4; ++r) {
                int c = mt * 16 + l4 * 4 + r;
                S[c * MPAD + o] = f2bf((acc[mt][nt][r] + bsv) * g + be);
            }
    }
    __syncthreads();

    const unsigned short* W2p = HW1b + (size_t)h * 65536;
    #pragma unroll
    for (int mt = 0; mt < 4; ++mt)
        #pragma unroll
        for (int nt = 0; nt < 4; ++nt) acc[mt][nt] = 0.f;
    for (int kc = 0; kc < 8; ++kc) {
        bf16x8 bfr[4];
        #pragma unroll
        for (int nt = 0; nt < 4; ++nt) {
            int kk = w * 64 + nt * 16 + l15;
            bfr[nt] = *(const bf16x8*)(W2p + (size_t)kk * 256 + kc * 32 + l4 * 8);
        }
        #pragma unroll
        for (int mt = 0; mt < 4; ++mt) {
            bf16x8 afr = *(const bf16x8*)&S[(mt * 16 + l15) * MPAD + kc * 32 + l4 * 8];
            #pragma unroll
            for (int nt = 0; nt < 4; ++nt)
                acc[mt][nt] = __builtin_amdgcn_mfma_f32_16x16x32_bf16(afr, bfr[nt], acc[mt][nt], 0, 0, 0);
        }
    }
    #pragma unroll
    for (int nt = 0; nt < 4; ++nt) {
        int kk = w * 64 + nt * 16 + l15;
        float hb = Hb1[(size_t)h * 256 + kk];
        #pragma unroll
        for (int mt = 0; mt < 4; ++mt)
            #pragma unroll
            for (int r = 0; r < 4; ++r) {
                int c = mt * 16 + l4 * 4 + r;
                XT[c * MPAD + kk] = f2bf(gelu_exact(acc[mt][nt][r] + hb));
            }
    }
    __syncthreads();

    const unsigned short* W3p = HW2b + (size_t)h * 65536;
    #pragma unroll
    for (int mt = 0; mt < 4; ++mt)
        #pragma unroll
        for (int nt = 0; nt < 4; ++nt) acc[mt][nt] = 0.f;
    for (int kc = 0; kc < 8; ++kc) {
        bf16x8 bfr[4];
        #pragma unroll
        for (int nt = 0; nt < 4; ++nt) {
            int p = w * 64 + nt * 16 + l15;
            bfr[nt] = *(const bf16x8*)(W3p + (size_t)p * 256 + kc * 32 + l4 * 8);
        }
        #pragma unroll
        for (int mt = 0; mt < 4; ++mt) {
            bf16x8 afr = *(const bf16x8*)&XT[(mt * 16 + l15) * MPAD + kc * 32 + l4 * 8];
            #pragma unroll
            for (int nt = 0; nt < 4; ++nt)
                acc[mt][nt] = __builtin_amdgcn_mfma_f32_16x16x32_bf16(afr, bfr[nt], acc[mt][nt], 0, 0, 0);
        }
    }
    #pragma unroll
    for (int nt = 0; nt < 4; ++nt) {
        int p = w * 64 + nt * 16 + l15;
        float hb = Hb2[(size_t)h * 256 + p];
        const float* xr = x + ((size_t)(b * 256 + p)) * 514 + h * 64;
        float* orow = out + ((size_t)(b * 256 + p)) * 514 + h * 64;
        #pragma unroll
        for (int mt = 0; mt < 4; ++mt) {
            int c0 = mt * 16 + l4 * 4;
            f32x2 x0 = *(const f32x2*)(xr + c0);
            f32x2 x1 = *(const f32x2*)(xr + c0 + 2);
            f32x2 o0, o1;
            o0.x = acc[mt][nt][0] + hb + x0.x;
            o0.y = acc[mt][nt][1] + hb + x0.y;
            o1.x = acc[mt][nt][2] + hb + x1.x;
            o1.y = acc[mt][nt][3] + hb + x1.y;
            *(f32x2*)(orow + c0) = o0;
            *(f32x2*)(orow + c0 + 2) = o1;
        }
    }
}

// ---------------------------------------------------------------------------
// FFN v3: one workgroup (256 thr, 4 waves) per 64 tokens.
//  Key change vs v2: big per-wave output tiles for fragment reuse.
//   - 16 chunks of 128 dff.
//   - stage-1: 2x2 wave grid, wave tile 32tok x 64dff (2x4 MFMA tiles):
//       A-frag reused x4, 32 XT-reads per 128 MFMA (was 1:1).
//   - stage-2: wave tile 64tok x 128fcol (4x8 tiles): 16 G-reads per 128 MFMA.
//  LDS: XT 64KB (swizzled) + G 16KB (swizzled) = 80KB -> 2 blocks/CU.
// ---------------------------------------------------------------------------
__global__ __launch_bounds__(256, 2) void ffn_kernel(
    const unsigned short* __restrict__ FW1b,   // [2048][512]
    const unsigned int* __restrict__ FWscb,    // [2048] bf16 pairs (cols 512/513)
    const unsigned short* __restrict__ FW2b,   // [512][2048]
    const float* __restrict__ Fb1, const float* __restrict__ Fb2,
    float* __restrict__ io) {
    __shared__ char XT[65536];  // [64 tok][1024 B] swizzled: byte ^= (row&7)<<4
    __shared__ char G[16384];   // [64 tok][256 B]  swizzled: byte ^= (tok&7)<<4

    const size_t r0 = (size_t)blockIdx.x * 64;
    const int tid = threadIdx.x;
    const int lane = tid & 63;
    const int w = tid >> 6;
    const int l15 = lane & 15;
    const int l4 = lane >> 4;
    const int wr = w >> 1;  // stage-1 token half
    const int wc = w & 1;   // stage-1 dff half

    // ---- stage XT: 4 threads per row, swizzled b128 writes ----
    {
        const int row = tid >> 2, q = tid & 3;
        const float* src = io + (r0 + row) * 514;
        char* drow = XT + row * 1024;
        const int sw = (row & 7) << 4;
        #pragma unroll
        for (int it = 0; it < 16; ++it) {
            int c = q * 128 + it * 8;
            f32x4 v0 = *(const f32x4*)(src + c);
            f32x4 v1 = *(const f32x4*)(src + c + 4);
            uint4 p;
            p.x = pack2(v0.x, v0.y);
            p.y = pack2(v0.z, v0.w);
            p.z = pack2(v1.x, v1.y);
            p.w = pack2(v1.z, v1.w);
            *(uint4*)(drow + ((2 * c) ^ sw)) = p;
        }
    }

    // ---- sc A-fragments for stage-1 (toks wr*32 + mt*16 + l15) ----
    bf16x8 asc[2];
    #pragma unroll
    for (int mt = 0; mt < 2; ++mt) {
        unsigned int v = 0u;
        if (l4 == 0) {
            const float* p = io + (r0 + wr * 32 + mt * 16 + l15) * 514 + 512;
            v = pack2(p[0], p[1]);
        }
        asc[mt] = bf8_from2(v);
    }

    f32x4 F[4][8];
    #pragma unroll
    for (int mt = 0; mt < 4; ++mt)
        #pragma unroll
        for (int nt = 0; nt < 8; ++nt) F[mt][nt] = 0.f;

    __syncthreads();

    for (int dc = 0; dc < 16; ++dc) {
        const int ndffbase = dc * 128 + wc * 64;

        // ---- stage 1: a1[2][4] = XT(32x512) @ FW1chunk^T(64x512) ----
        f32x4 a1[2][4];
        #pragma unroll
        for (int mt = 0; mt < 2; ++mt)
            #pragma unroll
            for (int nt = 0; nt < 4; ++nt) a1[mt][nt] = 0.f;
        #pragma unroll 4
        for (int kc = 0; kc < 16; ++kc) {
            bf16x8 b[4];
            #pragma unroll
            for (int nt = 0; nt < 4; ++nt)
                b[nt] = *(const bf16x8*)(FW1b + (size_t)(ndffbase + nt * 16 + l15) * 512 + kc * 32 + l4 * 8);
            #pragma unroll
            for (int mt = 0; mt < 2; ++mt) {
                int row = wr * 32 + mt * 16 + l15;
                const char* ap = XT + row * 1024 + ((kc * 64 + l4 * 16) ^ ((row & 7) << 4));
                bf16x8 af = *(const bf16x8*)ap;
                #pragma unroll
                for (int nt = 0; nt < 4; ++nt)
                    a1[mt][nt] = __builtin_amdgcn_mfma_f32_16x16x32_bf16(af, b[nt], a1[mt][nt], 0, 0, 0);
            }
        }
        // sc contribution
        #pragma unroll
        for (int nt = 0; nt < 4; ++nt) {
            bf16x8 bsc = bf8_from2(l4 == 0 ? FWscb[ndffbase + nt * 16 + l15] : 0u);
            #pragma unroll
            for (int mt = 0; mt < 2; ++mt)
                a1[mt][nt] = __builtin_amdgcn_mfma_f32_16x16x32_bf16(asc[mt], bsc, a1[mt][nt], 0, 0, 0);
        }

        // ---- gelu + bias -> G (swizzled b16 writes) ----
        #pragma unroll
        for (int nt = 0; nt < 4; ++nt) {
            float fb1 = Fb1[ndffbase + nt * 16 + l15];
            int dffc = wc * 64 + nt * 16 + l15;
            #pragma unroll
            for (int mt = 0; mt < 2; ++mt)
                #pragma unroll
                for (int r = 0; r < 4; ++r) {
                    int tok = wr * 32 + mt * 16 + l4 * 4 + r;
                    float v = gelu_exact(a1[mt][nt][r] + fb1);
                    *(unsigned short*)(G + tok * 256 + ((dffc * 2) ^ ((tok & 7) << 4))) = f2bf(v);
                }
        }
        __syncthreads();

        // ---- stage 2: F(64x128 per wave) += G(64x128) @ FW2chunk^T ----
        #pragma unroll
        for (int kc2 = 0; kc2 < 4; ++kc2) {
            bf16x8 ag[4];
            #pragma unroll
            for (int mt = 0; mt < 4; ++mt) {
                int tok = mt * 16 + l15;
                ag[mt] = *(const bf16x8*)(G + tok * 256 + ((kc2 * 64 + l4 * 16) ^ ((tok & 7) << 4)));
            }
            #pragma unroll
            for (int nt = 0; nt < 8; ++nt) {
                int n = w * 128 + nt * 16 + l15;
                bf16x8 b2 = *(const bf16x8*)(FW2b + (size_t)n * 2048 + dc * 128 + kc2 * 32 + l4 * 8);
                #pragma unroll
                for (int mt = 0; mt < 4; ++mt)
                    F[mt][nt] = __builtin_amdgcn_mfma_f32_16x16x32_bf16(ag[mt], b2, F[mt][nt], 0, 0, 0);
            }
        }
        __syncthreads();
    }

    // ---- epilogue: in-place residual add ----
    #pragma unroll
    for (int nt = 0; nt < 8; ++nt) {
        int col = w * 128 + nt * 16 + l15;
        float fb = Fb2[col];
        #pragma unroll
        for (int mt = 0; mt < 4; ++mt)
            #pragma unroll
            for (int r = 0; r < 4; ++r) {
                size_t row = r0 + mt * 16 + l4 * 4 + r;
                float* p = io + row * 514 + col;
                *p = F[mt][nt][r] + fb + *p;
            }
    }
}

// ---------------------------------------------------------------------------
extern "C" void kernel_launch(void* const* d_in, const int* in_sizes, int n_in,
                              void* d_out, int out_size, void* d_ws, size_t ws_size,
                              hipStream_t stream) {
    const float* x = (const float*)d_in[0];
    const float* Ws = (const float*)d_in[1];
    const float* bs = (const float*)d_in[2];
    const float* LW1 = (const float*)d_in[3];
    const float* Lb1 = (const float*)d_in[4];
    const float* LW2 = (const float*)d_in[5];
    const float* Lb2 = (const float*)d_in[6];
    const float* HW1 = (const float*)d_in[7];
    const float* Hb1 = (const float*)d_in[8];
    const float* HW2 = (const float*)d_in[9];
    const float* Hb2 = (const float*)d_in[10];
    const float* FW1 = (const float*)d_in[11];
    const float* Fb1 = (const float*)d_in[12];
    const float* FW2 = (const float*)d_in[13];
    const float* Fb2 = (const float*)d_in[14];
    float* out = (float*)d_out;

    char* ws = (char*)d_ws;
    unsigned short* Wsb = (unsigned short*)(ws);                 // 131072 B
    unsigned short* HW1b = (unsigned short*)(ws + 131072);       // 1048576 B
    unsigned short* HW2b = (unsigned short*)(ws + 1179648);      // 1048576 B
    unsigned short* FW1b = (unsigned short*)(ws + 2228224);      // 2048*512*2 B
    unsigned short* FW2b = (unsigned short*)(ws + 4325376);      // 512*2048*2 B
    unsigned int* FWscb = (unsigned int*)(ws + 6422528);         // 8192 B
    float* gb = (float*)(ws + 6430720);                          // 524288 B

    cast_bf16_kernel<<<256, 256, 0, stream>>>(Ws, Wsb, 65536);
    cast_bf16_kernel<<<2048, 256, 0, stream>>>(HW1, HW1b, 524288);
    cast_bf16_kernel<<<2048, 256, 0, stream>>>(HW2, HW2b, 524288);
    cast_bf16_kernel<<<4096, 256, 0, stream>>>(FW2, FW2b, 1048576);
    cast_fw1_kernel<<<4096, 256, 0, stream>>>(FW1, FW1b);
    cast_fwsc_kernel<<<8, 256, 0, stream>>>(FW1, FWscb);
    gb_kernel<<<256, 256, 0, stream>>>(x, LW1, Lb1, LW2, Lb2, gb);
    sc_copy_kernel<<<256, 256, 0, stream>>>(x, out);

    mixer_kernel<<<2048, 256, 0, stream>>>(x, bs, Hb1, Hb2, Wsb, HW1b, HW2b, gb, out);
    ffn_kernel<<<1024, 256, 0, stream>>>(FW1b, FWscb, FW2b, Fb1, Fb2, out);
}

// Round 4
// 904.956 us; speedup vs baseline: 1.2165x; 1.2165x over previous
//
#include <hip/hip_runtime.h>
#include <math.h>

typedef __attribute__((ext_vector_type(8))) __bf16 bf16x8;
typedef __attribute__((ext_vector_type(4))) float f32x4;
typedef __attribute__((ext_vector_type(2))) float f32x2;

#define DEV __device__ __forceinline__

typedef __attribute__((address_space(3))) unsigned int lds_u32;
typedef __attribute__((address_space(1))) unsigned int glb_u32;

DEV unsigned short f2bf(float f) {
    unsigned int u = __builtin_bit_cast(unsigned int, f);
    u += 0x7FFFu + ((u >> 16) & 1u);
    return (unsigned short)(u >> 16);
}
DEV unsigned int pack2(float a, float b) {
    return (unsigned int)f2bf(a) | ((unsigned int)f2bf(b) << 16);
}
DEV float gelu_exact(float v) {
    return 0.5f * v * (1.0f + erff(v * 0.70710678118654752f));
}

// ---------------------------------------------------------------------------
// small prep kernels
// ---------------------------------------------------------------------------
__global__ void cast_bf16_kernel(const float* __restrict__ src,
                                 unsigned short* __restrict__ dst, int n) {
    int i = blockIdx.x * 256 + threadIdx.x;
    if (i < n) dst[i] = f2bf(src[i]);
}

// FW1 (2048 x 514) -> bf16 [2048][512] (cols 0..511 only)
__global__ void cast_fw1_kernel(const float* __restrict__ src,
                                unsigned short* __restrict__ dst) {
    int i = blockIdx.x * 256 + threadIdx.x;
    if (i < 2048 * 512) {
        int row = i >> 9, k = i & 511;
        dst[i] = f2bf(src[row * 514 + k]);
    }
}

// io rows (f32, stride 514) cols 0..511 -> Xb bf16 [65536][512]
__global__ void cast_io_kernel(const float* __restrict__ io,
                               unsigned short* __restrict__ Xb) {
    int i = blockIdx.x * 256 + threadIdx.x;  // one thread per 8 elements
    int row = i >> 6;
    int c8 = (i & 63) * 8;
    const float* s = io + (size_t)row * 514 + c8;
    f32x2 a = *(const f32x2*)(s + 0);
    f32x2 b = *(const f32x2*)(s + 2);
    f32x2 c = *(const f32x2*)(s + 4);
    f32x2 d = *(const f32x2*)(s + 6);
    uint4 p;
    p.x = pack2(a.x, a.y);
    p.y = pack2(b.x, b.y);
    p.z = pack2(c.x, c.y);
    p.w = pack2(d.x, d.y);
    *(uint4*)(Xb + (size_t)row * 512 + c8) = p;
}

// per-batch modulation: gb[b][0..255]=gamma, gb[b][256..511]=beta
__global__ void gb_kernel(const float* __restrict__ x,
                          const float* __restrict__ LW1, const float* __restrict__ Lb1,
                          const float* __restrict__ LW2, const float* __restrict__ Lb2,
                          float* __restrict__ gb) {
    __shared__ float t[512];
    int b = blockIdx.x, tid = threadIdx.x;
    float s0 = x[((size_t)b * 256 + 128) * 514 + 512];
    float s1 = x[((size_t)b * 256 + 128) * 514 + 513];
    for (int j = tid; j < 512; j += 256)
        t[j] = gelu_exact(LW1[j * 2] * s0 + LW1[j * 2 + 1] * s1 + Lb1[j]);
    __syncthreads();
    for (int i = tid; i < 512; i += 256) {
        float a = Lb2[i];
        const float* wr = LW2 + (size_t)i * 512;
        for (int j = 0; j < 512; ++j) a += wr[j] * t[j];
        gb[(size_t)b * 512 + i] = a;
    }
}

// sc passthrough columns 512,513 of output
__global__ void sc_copy_kernel(const float* __restrict__ x, float* __restrict__ out) {
    size_t idx = (size_t)blockIdx.x * 256 + threadIdx.x;
    size_t off = idx * 514 + 512;
    *(f32x2*)(out + off) = *(const f32x2*)(x + off);
}

// ---------------------------------------------------------------------------
// mixer: one workgroup per (b,h). (unchanged — passes, ~150us, later target)
// ---------------------------------------------------------------------------
#define MPAD 264

__global__ __launch_bounds__(256, 2) void mixer_kernel(
    const float* __restrict__ x, const float* __restrict__ bs,
    const float* __restrict__ Hb1, const float* __restrict__ Hb2,
    const unsigned short* __restrict__ Wsb,
    const unsigned short* __restrict__ HW1b,
    const unsigned short* __restrict__ HW2b,
    const float* __restrict__ gb,
    float* __restrict__ out) {
    __shared__ unsigned short XT[64 * MPAD];
    __shared__ unsigned short S[64 * MPAD];

    const int bid = blockIdx.x;
    const int b = bid >> 3;
    const int h = bid & 7;
    const int tid = threadIdx.x;
    const int lane = tid & 63;
    const int w = tid >> 6;
    const int l15 = lane & 15;
    const int l4 = lane >> 4;

    {
        const int c = lane;
        const float* xp = x + ((size_t)b * 256) * 514 + (size_t)h * 64 + c;
        for (int i = 0; i < 32; ++i) {
            int p = (i * 4 + w) * 2;
            float v0 = xp[(size_t)p * 514];
            float v1 = xp[(size_t)(p + 1) * 514];
            *(unsigned int*)&XT[c * MPAD + p] = pack2(v0, v1);
        }
    }
    __syncthreads();

    f32x4 acc[4][4];

    #pragma unroll
    for (int mt = 0; mt < 4; ++mt)
        #pragma unroll
        for (int nt = 0; nt < 4; ++nt) acc[mt][nt] = 0.f;
    for (int kc = 0; kc < 8; ++kc) {
        bf16x8 bfr[4];
        #pragma unroll
        for (int nt = 0; nt < 4; ++nt) {
            int o = w * 64 + nt * 16 + l15;
            bfr[nt] = *(const bf16x8*)(Wsb + (size_t)o * 256 + kc * 32 + l4 * 8);
        }
        #pragma unroll
        for (int mt = 0; mt < 4; ++mt) {
            bf16x8 afr = *(const bf16x8*)&XT[(mt * 16 + l15) * MPAD + kc * 32 + l4 * 8];
            #pragma unroll
            for (int nt = 0; nt < 4; ++nt)
                acc[mt][nt] = __builtin_amdgcn_mfma_f32_16x16x32_bf16(afr, bfr[nt], acc[mt][nt], 0, 0, 0);
        }
    }
    #pragma unroll
    for (int nt = 0; nt < 4; ++nt) {
        int o = w * 64 + nt * 16 + l15;
        float bsv = bs[o];
        float g = gb[(size_t)b * 512 + o];
        float be = gb[(size_t)b * 512 + 256 + o];
        #pragma unroll
        for (int mt = 0; mt < 4; ++mt)
            #pragma unroll
            for (int r = 0; r < 4; ++r) {
                int c = mt * 16 + l4 * 4 + r;
                S[c * MPAD + o] = f2bf((acc[mt][nt][r] + bsv) * g + be);
            }
    }
    __syncthreads();

    const unsigned short* W2p = HW1b + (size_t)h * 65536;
    #pragma unroll
    for (int mt = 0; mt < 4; ++mt)
        #pragma unroll
        for (int nt = 0; nt < 4; ++nt) acc[mt][nt] = 0.f;
    for (int kc = 0; kc < 8; ++kc) {
        bf16x8 bfr[4];
        #pragma unroll
        for (int nt = 0; nt < 4; ++nt) {
            int kk = w * 64 + nt * 16 + l15;
            bfr[nt] = *(const bf16x8*)(W2p + (size_t)kk * 256 + kc * 32 + l4 * 8);
        }
        #pragma unroll
        for (int mt = 0; mt < 4; ++mt) {
            bf16x8 afr = *(const bf16x8*)&S[(mt * 16 + l15) * MPAD + kc * 32 + l4 * 8];
            #pragma unroll
            for (int nt = 0; nt < 4; ++nt)
                acc[mt][nt] = __builtin_amdgcn_mfma_f32_16x16x32_bf16(afr, bfr[nt], acc[mt][nt], 0, 0, 0);
        }
    }
    #pragma unroll
    for (int nt = 0; nt < 4; ++nt) {
        int kk = w * 64 + nt * 16 + l15;
        float hb = Hb1[(size_t)h * 256 + kk];
        #pragma unroll
        for (int mt = 0; mt < 4; ++mt)
            #pragma unroll
            for (int r = 0; r < 4; ++r) {
                int c = mt * 16 + l4 * 4 + r;
                XT[c * MPAD + kk] = f2bf(gelu_exact(acc[mt][nt][r] + hb));
            }
    }
    __syncthreads();

    const unsigned short* W3p = HW2b + (size_t)h * 65536;
    #pragma unroll
    for (int mt = 0; mt < 4; ++mt)
        #pragma unroll
        for (int nt = 0; nt < 4; ++nt) acc[mt][nt] = 0.f;
    for (int kc = 0; kc < 8; ++kc) {
        bf16x8 bfr[4];
        #pragma unroll
        for (int nt = 0; nt < 4; ++nt) {
            int p = w * 64 + nt * 16 + l15;
            bfr[nt] = *(const bf16x8*)(W3p + (size_t)p * 256 + kc * 32 + l4 * 8);
        }
        #pragma unroll
        for (int mt = 0; mt < 4; ++mt) {
            bf16x8 afr = *(const bf16x8*)&XT[(mt * 16 + l15) * MPAD + kc * 32 + l4 * 8];
            #pragma unroll
            for (int nt = 0; nt < 4; ++nt)
                acc[mt][nt] = __builtin_amdgcn_mfma_f32_16x16x32_bf16(afr, bfr[nt], acc[mt][nt], 0, 0, 0);
        }
    }
    #pragma unroll
    for (int nt = 0; nt < 4; ++nt) {
        int p = w * 64 + nt * 16 + l15;
        float hb = Hb2[(size_t)h * 256 + p];
        const float* xr = x + ((size_t)(b * 256 + p)) * 514 + h * 64;
        float* orow = out + ((size_t)(b * 256 + p)) * 514 + h * 64;
        #pragma unroll
        for (int mt = 0; mt < 4; ++mt) {
            int c0 = mt * 16 + l4 * 4;
            f32x2 x0 = *(const f32x2*)(xr + c0);
            f32x2 x1 = *(const f32x2*)(xr + c0 + 2);
            f32x2 o0, o1;
            o0.x = acc[mt][nt][0] + hb + x0.x;
            o0.y = acc[mt][nt][1] + hb + x0.y;
            o1.x = acc[mt][nt][2] + hb + x1.x;
            o1.y = acc[mt][nt][3] + hb + x1.y;
            *(f32x2*)(orow + c0) = o0;
            *(f32x2*)(orow + c0 + 2) = o1;
        }
    }
}

// ---------------------------------------------------------------------------
// m97-template GEMM pieces: 128x128 tile, BK=64, double-buffered LDS for A+B,
// global_load_lds width 16 with pre-swizzled source, XOR-swizzled ds_read.
// ---------------------------------------------------------------------------

// stage a 128row x 64col bf16 tile into lbuf (16KB), rows row0.., col elems k0..
DEV void stage_tile(const unsigned short* g, size_t gstride, int row0, int k0,
                    char* lbuf, int w, int lane) {
    const int slot = lane & 7;
    const int r8 = lane >> 3;
    const int swz = ((slot ^ (r8 & 7)) * 16);
    #pragma unroll
    for (int p = 0; p < 4; ++p) {
        int chunk = w * 4 + p;  // 0..15, 8 rows each
        int row = chunk * 8 + r8;
        const char* src = (const char*)(g + (size_t)(row0 + row) * gstride + k0) + swz;
        __builtin_amdgcn_global_load_lds((const glb_u32*)src,
                                         (lds_u32*)(lbuf + chunk * 1024), 16, 0, 0);
    }
}

DEV void compute_step(const char* Ab, const char* Bb, int wr, int wc, int l15, int l4,
                      f32x4 acc[4][4]) {
    #pragma unroll
    for (int kk = 0; kk < 2; ++kk) {
        bf16x8 af[4], bf[4];
        #pragma unroll
        for (int mt = 0; mt < 4; ++mt) {
            int row = wr * 64 + mt * 16 + l15;
            af[mt] = *(const bf16x8*)(Ab + row * 128 + ((kk * 64 + l4 * 16) ^ ((row & 7) << 4)));
        }
        #pragma unroll
        for (int nt = 0; nt < 4; ++nt) {
            int row = wc * 64 + nt * 16 + l15;
            bf[nt] = *(const bf16x8*)(Bb + row * 128 + ((kk * 64 + l4 * 16) ^ ((row & 7) << 4)));
        }
        #pragma unroll
        for (int mt = 0; mt < 4; ++mt)
            #pragma unroll
            for (int nt = 0; nt < 4; ++nt)
                acc[mt][nt] = __builtin_amdgcn_mfma_f32_16x16x32_bf16(af[mt], bf[nt], acc[mt][nt], 0, 0, 0);
    }
}

// GEMM1: G[Mp x 2048] = gelu( Xb[Mp x 512] @ FW1b^T + Fb1 + sc0*w512 + sc1*w513 )
__global__ __launch_bounds__(256, 2) void gemm1_kernel(
    const unsigned short* __restrict__ A,   // Xb + pass_m0*512
    const unsigned short* __restrict__ B,   // FW1b [2048][512]
    const float* __restrict__ Fb1,
    const float* __restrict__ FW1,          // f32 [2048][514] (cols 512/513)
    const float* __restrict__ io,           // f32 [65536][514] (sc cols)
    long pass_m0,
    unsigned short* __restrict__ G) {       // [Mp][2048]
    __shared__ __attribute__((aligned(16))) char Abuf[2][16384];
    __shared__ __attribute__((aligned(16))) char Bbuf[2][16384];

    const int bid = blockIdx.x;
    const int m0 = (bid >> 4) * 128;
    const int n0 = (bid & 15) * 128;
    const int tid = threadIdx.x;
    const int lane = tid & 63;
    const int w = tid >> 6;
    const int l15 = lane & 15;
    const int l4 = lane >> 4;
    const int wr = w >> 1, wc = w & 1;

    f32x4 acc[4][4];
    #pragma unroll
    for (int mt = 0; mt < 4; ++mt)
        #pragma unroll
        for (int nt = 0; nt < 4; ++nt) acc[mt][nt] = 0.f;

    stage_tile(A, 512, m0, 0, Abuf[0], w, lane);
    stage_tile(B, 512, n0, 0, Bbuf[0], w, lane);
    __syncthreads();

    for (int s = 0; s < 8; ++s) {
        int cur = s & 1;
        if (s + 1 < 8) {
            stage_tile(A, 512, m0, (s + 1) * 64, Abuf[cur ^ 1], w, lane);
            stage_tile(B, 512, n0, (s + 1) * 64, Bbuf[cur ^ 1], w, lane);
        }
        compute_step(Abuf[cur], Bbuf[cur], wr, wc, l15, l4, acc);
        __syncthreads();
    }

    // epilogue: bias + sc contribution + gelu -> bf16 G
    f32x2 scp[4][4];
    #pragma unroll
    for (int mt = 0; mt < 4; ++mt)
        #pragma unroll
        for (int r = 0; r < 4; ++r) {
            long rowg = pass_m0 + m0 + wr * 64 + mt * 16 + l4 * 4 + r;
            scp[mt][r] = *(const f32x2*)(io + rowg * 514 + 512);
        }
    #pragma unroll
    for (int nt = 0; nt < 4; ++nt) {
        int n = n0 + wc * 64 + nt * 16 + l15;
        float fb = Fb1[n];
        float w512 = FW1[(size_t)n * 514 + 512];
        float w513 = FW1[(size_t)n * 514 + 513];
        #pragma unroll
        for (int mt = 0; mt < 4; ++mt)
            #pragma unroll
            for (int r = 0; r < 4; ++r) {
                long row = m0 + wr * 64 + mt * 16 + l4 * 4 + r;  // pass-local
                float v = acc[mt][nt][r] + fb + scp[mt][r].x * w512 + scp[mt][r].y * w513;
                G[row * 2048 + n] = f2bf(gelu_exact(v));
            }
    }
}

// GEMM2: io[., 0..511] += G[Mp x 2048] @ FW2b^T + Fb2
__global__ __launch_bounds__(256, 2) void gemm2_kernel(
    const unsigned short* __restrict__ A,   // G [Mp][2048]
    const unsigned short* __restrict__ B,   // FW2b [512][2048]
    const float* __restrict__ Fb2,
    long pass_m0,
    float* __restrict__ io) {
    __shared__ __attribute__((aligned(16))) char Abuf[2][16384];
    __shared__ __attribute__((aligned(16))) char Bbuf[2][16384];

    const int bid = blockIdx.x;
    const int m0 = (bid >> 2) * 128;
    const int n0 = (bid & 3) * 128;
    const int tid = threadIdx.x;
    const int lane = tid & 63;
    const int w = tid >> 6;
    const int l15 = lane & 15;
    const int l4 = lane >> 4;
    const int wr = w >> 1, wc = w & 1;

    f32x4 acc[4][4];
    #pragma unroll
    for (int mt = 0; mt < 4; ++mt)
        #pragma unroll
        for (int nt = 0; nt < 4; ++nt) acc[mt][nt] = 0.f;

    stage_tile(A, 2048, m0, 0, Abuf[0], w, lane);
    stage_tile(B, 2048, n0, 0, Bbuf[0], w, lane);
    __syncthreads();

    for (int s = 0; s < 32; ++s) {
        int cur = s & 1;
        if (s + 1 < 32) {
            stage_tile(A, 2048, m0, (s + 1) * 64, Abuf[cur ^ 1], w, lane);
            stage_tile(B, 2048, n0, (s + 1) * 64, Bbuf[cur ^ 1], w, lane);
        }
        compute_step(Abuf[cur], Bbuf[cur], wr, wc, l15, l4, acc);
        __syncthreads();
    }

    // epilogue: bias + residual RMW into io
    #pragma unroll
    for (int nt = 0; nt < 4; ++nt) {
        int n = n0 + wc * 64 + nt * 16 + l15;
        float fb = Fb2[n];
        #pragma unroll
        for (int mt = 0; mt < 4; ++mt)
            #pragma unroll
            for (int r = 0; r < 4; ++r) {
                long rowg = pass_m0 + m0 + wr * 64 + mt * 16 + l4 * 4 + r;
                float* p = io + rowg * 514 + n;
                *p = acc[mt][nt][r] + fb + *p;
            }
    }
}

// ---------------------------------------------------------------------------
extern "C" void kernel_launch(void* const* d_in, const int* in_sizes, int n_in,
                              void* d_out, int out_size, void* d_ws, size_t ws_size,
                              hipStream_t stream) {
    const float* x = (const float*)d_in[0];
    const float* Ws = (const float*)d_in[1];
    const float* bs = (const float*)d_in[2];
    const float* LW1 = (const float*)d_in[3];
    const float* Lb1 = (const float*)d_in[4];
    const float* LW2 = (const float*)d_in[5];
    const float* Lb2 = (const float*)d_in[6];
    const float* HW1 = (const float*)d_in[7];
    const float* Hb1 = (const float*)d_in[8];
    const float* HW2 = (const float*)d_in[9];
    const float* Hb2 = (const float*)d_in[10];
    const float* FW1 = (const float*)d_in[11];
    const float* Fb1 = (const float*)d_in[12];
    const float* FW2 = (const float*)d_in[13];
    const float* Fb2 = (const float*)d_in[14];
    float* out = (float*)d_out;

    char* ws = (char*)d_ws;
    unsigned short* Wsb = (unsigned short*)(ws);                 // 131072 B
    unsigned short* HW1b = (unsigned short*)(ws + 131072);       // 1048576 B
    unsigned short* HW2b = (unsigned short*)(ws + 1179648);      // 1048576 B
    unsigned short* FW1b = (unsigned short*)(ws + 2228224);      // 2097152 B
    unsigned short* FW2b = (unsigned short*)(ws + 4325376);      // 2097152 B
    float* gb = (float*)(ws + 6422528);                          // 524288 B
    unsigned short* Xb = (unsigned short*)(ws + 6946816);        // 67108864 B
    unsigned short* Gbuf = (unsigned short*)(ws + 6946816 + 67108864);

    // pick pass count so G fits in remaining workspace
    const size_t fixed = 6946816 + 67108864;
    int npass = 32;
    for (int np = 4; np <= 32; np *= 2) {
        if (fixed + (size_t)268435456 / np <= ws_size) { npass = np; break; }
    }
    const long Mtot = 65536;
    const long Mp = Mtot / npass;

    cast_bf16_kernel<<<256, 256, 0, stream>>>(Ws, Wsb, 65536);
    cast_bf16_kernel<<<2048, 256, 0, stream>>>(HW1, HW1b, 524288);
    cast_bf16_kernel<<<2048, 256, 0, stream>>>(HW2, HW2b, 524288);
    cast_bf16_kernel<<<4096, 256, 0, stream>>>(FW2, FW2b, 1048576);
    cast_fw1_kernel<<<4096, 256, 0, stream>>>(FW1, FW1b);
    gb_kernel<<<256, 256, 0, stream>>>(x, LW1, Lb1, LW2, Lb2, gb);
    sc_copy_kernel<<<256, 256, 0, stream>>>(x, out);

    mixer_kernel<<<2048, 256, 0, stream>>>(x, bs, Hb1, Hb2, Wsb, HW1b, HW2b, gb, out);

    cast_io_kernel<<<16384, 256, 0, stream>>>(out, Xb);

    for (int p = 0; p < npass; ++p) {
        long m0 = (long)p * Mp;
        gemm1_kernel<<<(int)(Mp / 128) * 16, 256, 0, stream>>>(
            Xb + m0 * 512, FW1b, Fb1, FW1, out, m0, Gbuf);
        gemm2_kernel<<<(int)(Mp / 128) * 4, 256, 0, stream>>>(
            Gbuf, FW2b, Fb2, m0, out);
    }
}

// Round 5
// 798.247 us; speedup vs baseline: 1.3791x; 1.1337x over previous
//
#include <hip/hip_runtime.h>
#include <math.h>

typedef __attribute__((ext_vector_type(8))) __bf16 bf16x8;
typedef __attribute__((ext_vector_type(4))) float f32x4;
typedef __attribute__((ext_vector_type(2))) float f32x2;

#define DEV __device__ __forceinline__

typedef __attribute__((address_space(3))) unsigned int lds_u32;
typedef __attribute__((address_space(1))) unsigned int glb_u32;

DEV unsigned short f2bf(float f) {
    unsigned int u = __builtin_bit_cast(unsigned int, f);
    u += 0x7FFFu + ((u >> 16) & 1u);
    return (unsigned short)(u >> 16);
}
DEV float bf2f(unsigned short u) {
    unsigned int v = (unsigned int)u << 16;
    return __builtin_bit_cast(float, v);
}
DEV unsigned int pack2(float a, float b) {
    return (unsigned int)f2bf(a) | ((unsigned int)f2bf(b) << 16);
}
DEV float gelu_exact(float v) {
    return 0.5f * v * (1.0f + erff(v * 0.70710678118654752f));
}
// tanh-form gelu as sigmoid: x * sigmoid(1.595769x + 0.0713548x^3); |err| <= 3e-3
DEV float gelu_fast(float x) {
    float z = 1.5957691216f * x + 0.0713548163f * x * x * x;
    float e = __expf(-z);
    return x * __builtin_amdgcn_rcpf(1.0f + e);
}

// ---------------------------------------------------------------------------
// small prep kernels
// ---------------------------------------------------------------------------
__global__ void cast_bf16_kernel(const float* __restrict__ src,
                                 unsigned short* __restrict__ dst, int n) {
    int i = blockIdx.x * 256 + threadIdx.x;
    if (i < n) dst[i] = f2bf(src[i]);
}

// FW1 (2048 x 514) -> bf16 [2048][512] (cols 0..511 only)
__global__ void cast_fw1_kernel(const float* __restrict__ src,
                                unsigned short* __restrict__ dst) {
    int i = blockIdx.x * 256 + threadIdx.x;
    if (i < 2048 * 512) {
        int row = i >> 9, k = i & 511;
        dst[i] = f2bf(src[row * 514 + k]);
    }
}

// per-batch modulation, tiled: block handles 8 batches x 512 outputs
__global__ void gb_kernel(const float* __restrict__ x,
                          const float* __restrict__ LW1, const float* __restrict__ Lb1,
                          const float* __restrict__ LW2, const float* __restrict__ Lb2,
                          float* __restrict__ gb) {
    __shared__ float t[8][512];
    const int b0 = blockIdx.x * 8, tid = threadIdx.x;
    for (int idx = tid; idx < 8 * 512; idx += 256) {
        int bb = idx >> 9, j = idx & 511;
        float s0 = x[((size_t)(b0 + bb) * 256 + 128) * 514 + 512];
        float s1 = x[((size_t)(b0 + bb) * 256 + 128) * 514 + 513];
        t[bb][j] = gelu_exact(LW1[j * 2] * s0 + LW1[j * 2 + 1] * s1 + Lb1[j]);
    }
    __syncthreads();
    const int i = tid;  // outputs i and i+256
    float a0[8], a1[8];
    float l0 = Lb2[i], l1 = Lb2[i + 256];
    #pragma unroll
    for (int bb = 0; bb < 8; ++bb) { a0[bb] = l0; a1[bb] = l1; }
    for (int j = 0; j < 512; ++j) {
        float w0 = LW2[(size_t)i * 512 + j];
        float w1 = LW2[(size_t)(i + 256) * 512 + j];
        #pragma unroll
        for (int bb = 0; bb < 8; ++bb) {
            a0[bb] += w0 * t[bb][j];
            a1[bb] += w1 * t[bb][j];
        }
    }
    #pragma unroll
    for (int bb = 0; bb < 8; ++bb) {
        gb[(size_t)(b0 + bb) * 512 + i] = a0[bb];
        gb[(size_t)(b0 + bb) * 512 + i + 256] = a1[bb];
    }
}

// sc passthrough: out cols 512/513 + packed scbuf[token][2]
__global__ void sc_copy_kernel(const float* __restrict__ x, float* __restrict__ out,
                               float* __restrict__ scbuf) {
    size_t idx = (size_t)blockIdx.x * 256 + threadIdx.x;
    size_t off = idx * 514 + 512;
    f32x2 v = *(const f32x2*)(x + off);
    *(f32x2*)(out + off) = v;
    *(f32x2*)(scbuf + idx * 2) = v;
}

// ---------------------------------------------------------------------------
// mixer: one workgroup per (b,h). Chain of three 64x256 @ 256x256 GEMMs.
//  v5: B-fragment register prefetch; gelu_fast; coalesced epilogue via ST LDS
//  bounce (f32-exact residual), fused bf16 Xb emission (replaces cast_io).
// ---------------------------------------------------------------------------
#define MPAD 264

__global__ __launch_bounds__(256, 2) void mixer_kernel(
    const float* __restrict__ x, const float* __restrict__ bs,
    const float* __restrict__ Hb1, const float* __restrict__ Hb2,
    const unsigned short* __restrict__ Wsb,
    const unsigned short* __restrict__ HW1b,
    const unsigned short* __restrict__ HW2b,
    const float* __restrict__ gb,
    float* __restrict__ out,
    unsigned short* __restrict__ Xb) {
    __shared__ __attribute__((aligned(16))) char smem[33792 + 34816];
    unsigned short* XT = (unsigned short*)smem;            // [64][264]
    unsigned short* S = (unsigned short*)(smem + 33792);   // [64][264]
    unsigned short* ST = S;                                // reused: [256][68]

    const int bid = blockIdx.x;
    const int b = bid >> 3;
    const int h = bid & 7;
    const int tid = threadIdx.x;
    const int lane = tid & 63;
    const int w = tid >> 6;
    const int l15 = lane & 15;
    const int l4 = lane >> 4;

    // ---- stage x^T into LDS as bf16: XT[c][p] ----
    {
        const int c = lane;
        const float* xp = x + ((size_t)b * 256) * 514 + (size_t)h * 64 + c;
        for (int i = 0; i < 32; ++i) {
            int p = (i * 4 + w) * 2;
            float v0 = xp[(size_t)p * 514];
            float v1 = xp[(size_t)(p + 1) * 514];
            *(unsigned int*)&XT[c * MPAD + p] = pack2(v0, v1);
        }
    }
    __syncthreads();

    f32x4 acc[4][4];

    // ---- stage 1: S[c][o] = (XT @ Ws^T + bs)*gamma + beta ----
    #pragma unroll
    for (int mt = 0; mt < 4; ++mt)
        #pragma unroll
        for (int nt = 0; nt < 4; ++nt) acc[mt][nt] = 0.f;
    {
        bf16x8 bnx[4];
        #pragma unroll
        for (int nt = 0; nt < 4; ++nt)
            bnx[nt] = *(const bf16x8*)(Wsb + (size_t)(w * 64 + nt * 16 + l15) * 256 + l4 * 8);
        for (int kc = 0; kc < 8; ++kc) {
            bf16x8 bcur[4];
            #pragma unroll
            for (int nt = 0; nt < 4; ++nt) bcur[nt] = bnx[nt];
            if (kc < 7) {
                #pragma unroll
                for (int nt = 0; nt < 4; ++nt)
                    bnx[nt] = *(const bf16x8*)(Wsb + (size_t)(w * 64 + nt * 16 + l15) * 256 + (kc + 1) * 32 + l4 * 8);
            }
            #pragma unroll
            for (int mt = 0; mt < 4; ++mt) {
                bf16x8 afr = *(const bf16x8*)&XT[(mt * 16 + l15) * MPAD + kc * 32 + l4 * 8];
                #pragma unroll
                for (int nt = 0; nt < 4; ++nt)
                    acc[mt][nt] = __builtin_amdgcn_mfma_f32_16x16x32_bf16(afr, bcur[nt], acc[mt][nt], 0, 0, 0);
            }
        }
    }
    #pragma unroll
    for (int nt = 0; nt < 4; ++nt) {
        int o = w * 64 + nt * 16 + l15;
        float bsv = bs[o];
        float g = gb[(size_t)b * 512 + o];
        float be = gb[(size_t)b * 512 + 256 + o];
        #pragma unroll
        for (int mt = 0; mt < 4; ++mt)
            #pragma unroll
            for (int r = 0; r < 4; ++r) {
                int c = mt * 16 + l4 * 4 + r;
                S[c * MPAD + o] = f2bf((acc[mt][nt][r] + bsv) * g + be);
            }
    }
    __syncthreads();

    // ---- stage 2: XT[c][kk] = gelu(S @ HW1[h]^T + Hb1[h]) ----
    const unsigned short* W2p = HW1b + (size_t)h * 65536;
    #pragma unroll
    for (int mt = 0; mt < 4; ++mt)
        #pragma unroll
        for (int nt = 0; nt < 4; ++nt) acc[mt][nt] = 0.f;
    {
        bf16x8 bnx[4];
        #pragma unroll
        for (int nt = 0; nt < 4; ++nt)
            bnx[nt] = *(const bf16x8*)(W2p + (size_t)(w * 64 + nt * 16 + l15) * 256 + l4 * 8);
        for (int kc = 0; kc < 8; ++kc) {
            bf16x8 bcur[4];
            #pragma unroll
            for (int nt = 0; nt < 4; ++nt) bcur[nt] = bnx[nt];
            if (kc < 7) {
                #pragma unroll
                for (int nt = 0; nt < 4; ++nt)
                    bnx[nt] = *(const bf16x8*)(W2p + (size_t)(w * 64 + nt * 16 + l15) * 256 + (kc + 1) * 32 + l4 * 8);
            }
            #pragma unroll
            for (int mt = 0; mt < 4; ++mt) {
                bf16x8 afr = *(const bf16x8*)&S[(mt * 16 + l15) * MPAD + kc * 32 + l4 * 8];
                #pragma unroll
                for (int nt = 0; nt < 4; ++nt)
                    acc[mt][nt] = __builtin_amdgcn_mfma_f32_16x16x32_bf16(afr, bcur[nt], acc[mt][nt], 0, 0, 0);
            }
        }
    }
    #pragma unroll
    for (int nt = 0; nt < 4; ++nt) {
        int kk = w * 64 + nt * 16 + l15;
        float hb = Hb1[(size_t)h * 256 + kk];
        #pragma unroll
        for (int mt = 0; mt < 4; ++mt)
            #pragma unroll
            for (int r = 0; r < 4; ++r) {
                int c = mt * 16 + l4 * 4 + r;
                XT[c * MPAD + kk] = f2bf(gelu_fast(acc[mt][nt][r] + hb));
            }
    }
    __syncthreads();

    // ---- stage 3: ST[p][c] = T @ HW2[h]^T + Hb2 (bf16) ----
    const unsigned short* W3p = HW2b + (size_t)h * 65536;
    #pragma unroll
    for (int mt = 0; mt < 4; ++mt)
        #pragma unroll
        for (int nt = 0; nt < 4; ++nt) acc[mt][nt] = 0.f;
    {
        bf16x8 bnx[4];
        #pragma unroll
        for (int nt = 0; nt < 4; ++nt)
            bnx[nt] = *(const bf16x8*)(W3p + (size_t)(w * 64 + nt * 16 + l15) * 256 + l4 * 8);
        for (int kc = 0; kc < 8; ++kc) {
            bf16x8 bcur[4];
            #pragma unroll
            for (int nt = 0; nt < 4; ++nt) bcur[nt] = bnx[nt];
            if (kc < 7) {
                #pragma unroll
                for (int nt = 0; nt < 4; ++nt)
                    bnx[nt] = *(const bf16x8*)(W3p + (size_t)(w * 64 + nt * 16 + l15) * 256 + (kc + 1) * 32 + l4 * 8);
            }
            #pragma unroll
            for (int mt = 0; mt < 4; ++mt) {
                bf16x8 afr = *(const bf16x8*)&XT[(mt * 16 + l15) * MPAD + kc * 32 + l4 * 8];
                #pragma unroll
                for (int nt = 0; nt < 4; ++nt)
                    acc[mt][nt] = __builtin_amdgcn_mfma_f32_16x16x32_bf16(afr, bcur[nt], acc[mt][nt], 0, 0, 0);
            }
        }
    }
    #pragma unroll
    for (int nt = 0; nt < 4; ++nt) {
        int p = w * 64 + nt * 16 + l15;
        float hb = Hb2[(size_t)h * 256 + p];
        #pragma unroll
        for (int mt = 0; mt < 4; ++mt) {
            ushort4 uv;
            uv.x = f2bf(acc[mt][nt][0] + hb);
            uv.y = f2bf(acc[mt][nt][1] + hb);
            uv.z = f2bf(acc[mt][nt][2] + hb);
            uv.w = f2bf(acc[mt][nt][3] + hb);
            *(ushort4*)(ST + p * 68 + mt * 16 + l4 * 4) = uv;
        }
    }
    __syncthreads();

    // ---- coalesced epilogue: out = ST + x (f32 residual), Xb = bf16(out) ----
    #pragma unroll
    for (int s = 0; s < 16; ++s) {
        int row = s * 16 + w * 4 + l4;
        ushort4 u = *(const ushort4*)(ST + row * 68 + l15 * 4);
        const float* xr = x + ((size_t)(b * 256 + row)) * 514 + h * 64 + l15 * 4;
        f32x2 xa = *(const f32x2*)xr;
        f32x2 xc = *(const f32x2*)(xr + 2);
        float o0 = bf2f(u.x) + xa.x;
        float o1 = bf2f(u.y) + xa.y;
        float o2 = bf2f(u.z) + xc.x;
        float o3 = bf2f(u.w) + xc.y;
        float* orow = out + ((size_t)(b * 256 + row)) * 514 + h * 64 + l15 * 4;
        f32x2 w0; w0.x = o0; w0.y = o1;
        f32x2 w1; w1.x = o2; w1.y = o3;
        *(f32x2*)orow = w0;
        *(f32x2*)(orow + 2) = w1;
        ushort4 xo;
        xo.x = f2bf(o0); xo.y = f2bf(o1); xo.z = f2bf(o2); xo.w = f2bf(o3);
        *(ushort4*)(Xb + ((size_t)(b * 256 + row)) * 512 + h * 64 + l15 * 4) = xo;
    }
}

// ---------------------------------------------------------------------------
// m97-template GEMM pieces (128x128 tile, BK=64, dbuf LDS, global_load_lds).
// ---------------------------------------------------------------------------
DEV void stage_tile(const unsigned short* g, size_t gstride, int row0, int k0,
                    char* lbuf, int w, int lane) {
    const int slot = lane & 7;
    const int r8 = lane >> 3;
    const int swz = ((slot ^ (r8 & 7)) * 16);
    #pragma unroll
    for (int p = 0; p < 4; ++p) {
        int chunk = w * 4 + p;
        int row = chunk * 8 + r8;
        const char* src = (const char*)(g + (size_t)(row0 + row) * gstride + k0) + swz;
        __builtin_amdgcn_global_load_lds((const glb_u32*)src,
                                         (lds_u32*)(lbuf + chunk * 1024), 16, 0, 0);
    }
}

DEV void compute_step(const char* Ab, const char* Bb, int wr, int wc, int l15, int l4,
                      f32x4 acc[4][4]) {
    #pragma unroll
    for (int kk = 0; kk < 2; ++kk) {
        bf16x8 af[4], bf[4];
        #pragma unroll
        for (int mt = 0; mt < 4; ++mt) {
            int row = wr * 64 + mt * 16 + l15;
            af[mt] = *(const bf16x8*)(Ab + row * 128 + ((kk * 64 + l4 * 16) ^ ((row & 7) << 4)));
        }
        #pragma unroll
        for (int nt = 0; nt < 4; ++nt) {
            int row = wc * 64 + nt * 16 + l15;
            bf[nt] = *(const bf16x8*)(Bb + row * 128 + ((kk * 64 + l4 * 16) ^ ((row & 7) << 4)));
        }
        #pragma unroll
        for (int mt = 0; mt < 4; ++mt)
            #pragma unroll
            for (int nt = 0; nt < 4; ++nt)
                acc[mt][nt] = __builtin_amdgcn_mfma_f32_16x16x32_bf16(af[mt], bf[nt], acc[mt][nt], 0, 0, 0);
    }
}

// GEMM1: G = gelu(Xb @ FW1b^T + Fb1 + sc0*w512 + sc1*w513)
__global__ __launch_bounds__(256, 2) void gemm1_kernel(
    const unsigned short* __restrict__ A,
    const unsigned short* __restrict__ B,
    const float* __restrict__ Fb1,
    const float* __restrict__ FW1,
    const float* __restrict__ scbuf,
    long pass_m0,
    unsigned short* __restrict__ G) {
    __shared__ __attribute__((aligned(16))) char Abuf[2][16384];
    __shared__ __attribute__((aligned(16))) char Bbuf[2][16384];

    const int nwg = gridDim.x;
    const int cpx = nwg >> 3;
    const int bid = (blockIdx.x & 7) * cpx + (blockIdx.x >> 3);  // XCD swizzle
    const int m0 = (bid >> 4) * 128;
    const int n0 = (bid & 15) * 128;
    const int tid = threadIdx.x;
    const int lane = tid & 63;
    const int w = tid >> 6;
    const int l15 = lane & 15;
    const int l4 = lane >> 4;
    const int wr = w >> 1, wc = w & 1;

    f32x4 acc[4][4];
    #pragma unroll
    for (int mt = 0; mt < 4; ++mt)
        #pragma unroll
        for (int nt = 0; nt < 4; ++nt) acc[mt][nt] = 0.f;

    stage_tile(A, 512, m0, 0, Abuf[0], w, lane);
    stage_tile(B, 512, n0, 0, Bbuf[0], w, lane);
    __syncthreads();

    for (int s = 0; s < 8; ++s) {
        int cur = s & 1;
        if (s + 1 < 8) {
            stage_tile(A, 512, m0, (s + 1) * 64, Abuf[cur ^ 1], w, lane);
            stage_tile(B, 512, n0, (s + 1) * 64, Bbuf[cur ^ 1], w, lane);
        }
        compute_step(Abuf[cur], Bbuf[cur], wr, wc, l15, l4, acc);
        __syncthreads();
    }

    f32x2 scp[4][4];
    #pragma unroll
    for (int mt = 0; mt < 4; ++mt)
        #pragma unroll
        for (int r = 0; r < 4; ++r) {
            long rowg = pass_m0 + m0 + wr * 64 + mt * 16 + l4 * 4 + r;
            scp[mt][r] = *(const f32x2*)(scbuf + rowg * 2);
        }
    #pragma unroll
    for (int nt = 0; nt < 4; ++nt) {
        int n = n0 + wc * 64 + nt * 16 + l15;
        float fb = Fb1[n];
        float w512 = FW1[(size_t)n * 514 + 512];
        float w513 = FW1[(size_t)n * 514 + 513];
        #pragma unroll
        for (int mt = 0; mt < 4; ++mt)
            #pragma unroll
            for (int r = 0; r < 4; ++r) {
                long row = m0 + wr * 64 + mt * 16 + l4 * 4 + r;
                float v = acc[mt][nt][r] + fb + scp[mt][r].x * w512 + scp[mt][r].y * w513;
                G[row * 2048 + n] = f2bf(gelu_fast(v));
            }
    }
}

// GEMM2: io[., 0..511] += G @ FW2b^T + Fb2
__global__ __launch_bounds__(256, 2) void gemm2_kernel(
    const unsigned short* __restrict__ A,
    const unsigned short* __restrict__ B,
    const float* __restrict__ Fb2,
    long pass_m0,
    float* __restrict__ io) {
    __shared__ __attribute__((aligned(16))) char Abuf[2][16384];
    __shared__ __attribute__((aligned(16))) char Bbuf[2][16384];

    const int nwg = gridDim.x;
    const int cpx = nwg >> 3;
    const int bid = (blockIdx.x & 7) * cpx + (blockIdx.x >> 3);  // XCD swizzle
    const int m0 = (bid >> 2) * 128;
    const int n0 = (bid & 3) * 128;
    const int tid = threadIdx.x;
    const int lane = tid & 63;
    const int w = tid >> 6;
    const int l15 = lane & 15;
    const int l4 = lane >> 4;
    const int wr = w >> 1, wc = w & 1;

    f32x4 acc[4][4];
    #pragma unroll
    for (int mt = 0; mt < 4; ++mt)
        #pragma unroll
        for (int nt = 0; nt < 4; ++nt) acc[mt][nt] = 0.f;

    stage_tile(A, 2048, m0, 0, Abuf[0], w, lane);
    stage_tile(B, 2048, n0, 0, Bbuf[0], w, lane);
    __syncthreads();

    for (int s = 0; s < 32; ++s) {
        int cur = s & 1;
        if (s + 1 < 32) {
            stage_tile(A, 2048, m0, (s + 1) * 64, Abuf[cur ^ 1], w, lane);
            stage_tile(B, 2048, n0, (s + 1) * 64, Bbuf[cur ^ 1], w, lane);
        }
        compute_step(Abuf[cur], Bbuf[cur], wr, wc, l15, l4, acc);
        __syncthreads();
    }

    #pragma unroll
    for (int nt = 0; nt < 4; ++nt) {
        int n = n0 + wc * 64 + nt * 16 + l15;
        float fb = Fb2[n];
        #pragma unroll
        for (int mt = 0; mt < 4; ++mt)
            #pragma unroll
            for (int r = 0; r < 4; ++r) {
                long rowg = pass_m0 + m0 + wr * 64 + mt * 16 + l4 * 4 + r;
                float* p = io + rowg * 514 + n;
                *p = acc[mt][nt][r] + fb + *p;
            }
    }
}

// ---------------------------------------------------------------------------
extern "C" void kernel_launch(void* const* d_in, const int* in_sizes, int n_in,
                              void* d_out, int out_size, void* d_ws, size_t ws_size,
                              hipStream_t stream) {
    const float* x = (const float*)d_in[0];
    const float* Ws = (const float*)d_in[1];
    const float* bs = (const float*)d_in[2];
    const float* LW1 = (const float*)d_in[3];
    const float* Lb1 = (const float*)d_in[4];
    const float* LW2 = (const float*)d_in[5];
    const float* Lb2 = (const float*)d_in[6];
    const float* HW1 = (const float*)d_in[7];
    const float* Hb1 = (const float*)d_in[8];
    const float* HW2 = (const float*)d_in[9];
    const float* Hb2 = (const float*)d_in[10];
    const float* FW1 = (const float*)d_in[11];
    const float* Fb1 = (const float*)d_in[12];
    const float* FW2 = (const float*)d_in[13];
    const float* Fb2 = (const float*)d_in[14];
    float* out = (float*)d_out;

    char* ws = (char*)d_ws;
    unsigned short* Wsb = (unsigned short*)(ws);                 // 131072 B
    unsigned short* HW1b = (unsigned short*)(ws + 131072);       // 1048576 B
    unsigned short* HW2b = (unsigned short*)(ws + 1179648);      // 1048576 B
    unsigned short* FW1b = (unsigned short*)(ws + 2228224);      // 2097152 B
    unsigned short* FW2b = (unsigned short*)(ws + 4325376);      // 2097152 B
    float* gb = (float*)(ws + 6422528);                          // 524288 B
    float* scbuf = (float*)(ws + 6946816);                       // 524288 B
    unsigned short* Xb = (unsigned short*)(ws + 7471104);        // 67108864 B
    unsigned short* Gbuf = (unsigned short*)(ws + 7471104 + 67108864);

    const size_t fixed = 7471104 + 67108864;
    int npass = 32;
    for (int np = 4; np <= 32; np *= 2) {
        if (fixed + (size_t)268435456 / np <= ws_size) { npass = np; break; }
    }
    const long Mtot = 65536;
    const long Mp = Mtot / npass;

    cast_bf16_kernel<<<256, 256, 0, stream>>>(Ws, Wsb, 65536);
    cast_bf16_kernel<<<2048, 256, 0, stream>>>(HW1, HW1b, 524288);
    cast_bf16_kernel<<<2048, 256, 0, stream>>>(HW2, HW2b, 524288);
    cast_bf16_kernel<<<4096, 256, 0, stream>>>(FW2, FW2b, 1048576);
    cast_fw1_kernel<<<4096, 256, 0, stream>>>(FW1, FW1b);
    gb_kernel<<<32, 256, 0, stream>>>(x, LW1, Lb1, LW2, Lb2, gb);
    sc_copy_kernel<<<256, 256, 0, stream>>>(x, out, scbuf);

    mixer_kernel<<<2048, 256, 0, stream>>>(x, bs, Hb1, Hb2, Wsb, HW1b, HW2b, gb, out, Xb);

    for (int p = 0; p < npass; ++p) {
        long m0 = (long)p * Mp;
        gemm1_kernel<<<(int)(Mp / 128) * 16, 256, 0, stream>>>(
            Xb + m0 * 512, FW1b, Fb1, FW1, scbuf, m0, Gbuf);
        gemm2_kernel<<<(int)(Mp / 128) * 4, 256, 0, stream>>>(
            Gbuf, FW2b, Fb2, m0, out);
    }
}

// Round 6
// 665.052 us; speedup vs baseline: 1.6553x; 1.2003x over previous
//
#include <hip/hip_runtime.h>
#include <math.h>

typedef __attribute__((ext_vector_type(8))) __bf16 bf16x8;
typedef __attribute__((ext_vector_type(4))) float f32x4;
typedef __attribute__((ext_vector_type(2))) float f32x2;

#define DEV __device__ __forceinline__

typedef __attribute__((address_space(3))) unsigned int lds_u32;
typedef __attribute__((address_space(1))) unsigned int glb_u32;

DEV unsigned short f2bf(float f) {
    unsigned int u = __builtin_bit_cast(unsigned int, f);
    u += 0x7FFFu + ((u >> 16) & 1u);
    return (unsigned short)(u >> 16);
}
DEV float bf2f(unsigned short u) {
    unsigned int v = (unsigned int)u << 16;
    return __builtin_bit_cast(float, v);
}
DEV unsigned int pack2(float a, float b) {
    return (unsigned int)f2bf(a) | ((unsigned int)f2bf(b) << 16);
}
DEV float gelu_exact(float v) {
    return 0.5f * v * (1.0f + erff(v * 0.70710678118654752f));
}
// tanh-form gelu via sigmoid: x * sigmoid(1.595769x + 0.0713548x^3); |err| <= 3e-3
DEV float gelu_fast(float x) {
    float z = 1.5957691216f * x + 0.0713548163f * x * x * x;
    float e = __expf(-z);
    return x * __builtin_amdgcn_rcpf(1.0f + e);
}

// ---------------------------------------------------------------------------
// small prep kernels
// ---------------------------------------------------------------------------
__global__ void cast_bf16_kernel(const float* __restrict__ src,
                                 unsigned short* __restrict__ dst, int n) {
    int i = blockIdx.x * 256 + threadIdx.x;
    if (i < n) dst[i] = f2bf(src[i]);
}

__global__ void cast_fw1_kernel(const float* __restrict__ src,
                                unsigned short* __restrict__ dst) {
    int i = blockIdx.x * 256 + threadIdx.x;
    if (i < 2048 * 512) {
        int row = i >> 9, k = i & 511;
        dst[i] = f2bf(src[row * 514 + k]);
    }
}

__global__ void gb_kernel(const float* __restrict__ x,
                          const float* __restrict__ LW1, const float* __restrict__ Lb1,
                          const float* __restrict__ LW2, const float* __restrict__ Lb2,
                          float* __restrict__ gb) {
    __shared__ float t[8][512];
    const int b0 = blockIdx.x * 8, tid = threadIdx.x;
    for (int idx = tid; idx < 8 * 512; idx += 256) {
        int bb = idx >> 9, j = idx & 511;
        float s0 = x[((size_t)(b0 + bb) * 256 + 128) * 514 + 512];
        float s1 = x[((size_t)(b0 + bb) * 256 + 128) * 514 + 513];
        t[bb][j] = gelu_exact(LW1[j * 2] * s0 + LW1[j * 2 + 1] * s1 + Lb1[j]);
    }
    __syncthreads();
    const int i = tid;
    float a0[8], a1[8];
    float l0 = Lb2[i], l1 = Lb2[i + 256];
    #pragma unroll
    for (int bb = 0; bb < 8; ++bb) { a0[bb] = l0; a1[bb] = l1; }
    for (int j = 0; j < 512; ++j) {
        float w0 = LW2[(size_t)i * 512 + j];
        float w1 = LW2[(size_t)(i + 256) * 512 + j];
        #pragma unroll
        for (int bb = 0; bb < 8; ++bb) {
            a0[bb] += w0 * t[bb][j];
            a1[bb] += w1 * t[bb][j];
        }
    }
    #pragma unroll
    for (int bb = 0; bb < 8; ++bb) {
        gb[(size_t)(b0 + bb) * 512 + i] = a0[bb];
        gb[(size_t)(b0 + bb) * 512 + i + 256] = a1[bb];
    }
}

__global__ void sc_copy_kernel(const float* __restrict__ x, float* __restrict__ out,
                               float* __restrict__ scbuf) {
    size_t idx = (size_t)blockIdx.x * 256 + threadIdx.x;
    size_t off = idx * 514 + 512;
    f32x2 v = *(const f32x2*)(x + off);
    *(f32x2*)(out + off) = v;
    *(f32x2*)(scbuf + idx * 2) = v;
}

// ---------------------------------------------------------------------------
// mixer: unchanged from round 5
// ---------------------------------------------------------------------------
#define MPAD 264

__global__ __launch_bounds__(256, 2) void mixer_kernel(
    const float* __restrict__ x, const float* __restrict__ bs,
    const float* __restrict__ Hb1, const float* __restrict__ Hb2,
    const unsigned short* __restrict__ Wsb,
    const unsigned short* __restrict__ HW1b,
    const unsigned short* __restrict__ HW2b,
    const float* __restrict__ gb,
    float* __restrict__ out,
    unsigned short* __restrict__ Xb) {
    __shared__ __attribute__((aligned(16))) char smem[33792 + 34816];
    unsigned short* XT = (unsigned short*)smem;
    unsigned short* S = (unsigned short*)(smem + 33792);
    unsigned short* ST = S;

    const int bid = blockIdx.x;
    const int b = bid >> 3;
    const int h = bid & 7;
    const int tid = threadIdx.x;
    const int lane = tid & 63;
    const int w = tid >> 6;
    const int l15 = lane & 15;
    const int l4 = lane >> 4;

    {
        const int c = lane;
        const float* xp = x + ((size_t)b * 256) * 514 + (size_t)h * 64 + c;
        for (int i = 0; i < 32; ++i) {
            int p = (i * 4 + w) * 2;
            float v0 = xp[(size_t)p * 514];
            float v1 = xp[(size_t)(p + 1) * 514];
            *(unsigned int*)&XT[c * MPAD + p] = pack2(v0, v1);
        }
    }
    __syncthreads();

    f32x4 acc[4][4];

    #pragma unroll
    for (int mt = 0; mt < 4; ++mt)
        #pragma unroll
        for (int nt = 0; nt < 4; ++nt) acc[mt][nt] = 0.f;
    {
        bf16x8 bnx[4];
        #pragma unroll
        for (int nt = 0; nt < 4; ++nt)
            bnx[nt] = *(const bf16x8*)(Wsb + (size_t)(w * 64 + nt * 16 + l15) * 256 + l4 * 8);
        for (int kc = 0; kc < 8; ++kc) {
            bf16x8 bcur[4];
            #pragma unroll
            for (int nt = 0; nt < 4; ++nt) bcur[nt] = bnx[nt];
            if (kc < 7) {
                #pragma unroll
                for (int nt = 0; nt < 4; ++nt)
                    bnx[nt] = *(const bf16x8*)(Wsb + (size_t)(w * 64 + nt * 16 + l15) * 256 + (kc + 1) * 32 + l4 * 8);
            }
            #pragma unroll
            for (int mt = 0; mt < 4; ++mt) {
                bf16x8 afr = *(const bf16x8*)&XT[(mt * 16 + l15) * MPAD + kc * 32 + l4 * 8];
                #pragma unroll
                for (int nt = 0; nt < 4; ++nt)
                    acc[mt][nt] = __builtin_amdgcn_mfma_f32_16x16x32_bf16(afr, bcur[nt], acc[mt][nt], 0, 0, 0);
            }
        }
    }
    #pragma unroll
    for (int nt = 0; nt < 4; ++nt) {
        int o = w * 64 + nt * 16 + l15;
        float bsv = bs[o];
        float g = gb[(size_t)b * 512 + o];
        float be = gb[(size_t)b * 512 + 256 + o];
        #pragma unroll
        for (int mt = 0; mt < 4; ++mt)
            #pragma unroll
            for (int r = 0; r < 4; ++r) {
                int c = mt * 16 + l4 * 4 + r;
                S[c * MPAD + o] = f2bf((acc[mt][nt][r] + bsv) * g + be);
            }
    }
    __syncthreads();

    const unsigned short* W2p = HW1b + (size_t)h * 65536;
    #pragma unroll
    for (int mt = 0; mt < 4; ++mt)
        #pragma unroll
        for (int nt = 0; nt < 4; ++nt) acc[mt][nt] = 0.f;
    {
        bf16x8 bnx[4];
        #pragma unroll
        for (int nt = 0; nt < 4; ++nt)
            bnx[nt] = *(const bf16x8*)(W2p + (size_t)(w * 64 + nt * 16 + l15) * 256 + l4 * 8);
        for (int kc = 0; kc < 8; ++kc) {
            bf16x8 bcur[4];
            #pragma unroll
            for (int nt = 0; nt < 4; ++nt) bcur[nt] = bnx[nt];
            if (kc < 7) {
                #pragma unroll
                for (int nt = 0; nt < 4; ++nt)
                    bnx[nt] = *(const bf16x8*)(W2p + (size_t)(w * 64 + nt * 16 + l15) * 256 + (kc + 1) * 32 + l4 * 8);
            }
            #pragma unroll
            for (int mt = 0; mt < 4; ++mt) {
                bf16x8 afr = *(const bf16x8*)&S[(mt * 16 + l15) * MPAD + kc * 32 + l4 * 8];
                #pragma unroll
                for (int nt = 0; nt < 4; ++nt)
                    acc[mt][nt] = __builtin_amdgcn_mfma_f32_16x16x32_bf16(afr, bcur[nt], acc[mt][nt], 0, 0, 0);
            }
        }
    }
    #pragma unroll
    for (int nt = 0; nt < 4; ++nt) {
        int kk = w * 64 + nt * 16 + l15;
        float hb = Hb1[(size_t)h * 256 + kk];
        #pragma unroll
        for (int mt = 0; mt < 4; ++mt)
            #pragma unroll
            for (int r = 0; r < 4; ++r) {
                int c = mt * 16 + l4 * 4 + r;
                XT[c * MPAD + kk] = f2bf(gelu_fast(acc[mt][nt][r] + hb));
            }
    }
    __syncthreads();

    const unsigned short* W3p = HW2b + (size_t)h * 65536;
    #pragma unroll
    for (int mt = 0; mt < 4; ++mt)
        #pragma unroll
        for (int nt = 0; nt < 4; ++nt) acc[mt][nt] = 0.f;
    {
        bf16x8 bnx[4];
        #pragma unroll
        for (int nt = 0; nt < 4; ++nt)
            bnx[nt] = *(const bf16x8*)(W3p + (size_t)(w * 64 + nt * 16 + l15) * 256 + l4 * 8);
        for (int kc = 0; kc < 8; ++kc) {
            bf16x8 bcur[4];
            #pragma unroll
            for (int nt = 0; nt < 4; ++nt) bcur[nt] = bnx[nt];
            if (kc < 7) {
                #pragma unroll
                for (int nt = 0; nt < 4; ++nt)
                    bnx[nt] = *(const bf16x8*)(W3p + (size_t)(w * 64 + nt * 16 + l15) * 256 + (kc + 1) * 32 + l4 * 8);
            }
            #pragma unroll
            for (int mt = 0; mt < 4; ++mt) {
                bf16x8 afr = *(const bf16x8*)&XT[(mt * 16 + l15) * MPAD + kc * 32 + l4 * 8];
                #pragma unroll
                for (int nt = 0; nt < 4; ++nt)
                    acc[mt][nt] = __builtin_amdgcn_mfma_f32_16x16x32_bf16(afr, bcur[nt], acc[mt][nt], 0, 0, 0);
            }
        }
    }
    #pragma unroll
    for (int nt = 0; nt < 4; ++nt) {
        int p = w * 64 + nt * 16 + l15;
        float hb = Hb2[(size_t)h * 256 + p];
        #pragma unroll
        for (int mt = 0; mt < 4; ++mt) {
            ushort4 uv;
            uv.x = f2bf(acc[mt][nt][0] + hb);
            uv.y = f2bf(acc[mt][nt][1] + hb);
            uv.z = f2bf(acc[mt][nt][2] + hb);
            uv.w = f2bf(acc[mt][nt][3] + hb);
            *(ushort4*)(ST + p * 68 + mt * 16 + l4 * 4) = uv;
        }
    }
    __syncthreads();

    #pragma unroll
    for (int s = 0; s < 16; ++s) {
        int row = s * 16 + w * 4 + l4;
        ushort4 u = *(const ushort4*)(ST + row * 68 + l15 * 4);
        const float* xr = x + ((size_t)(b * 256 + row)) * 514 + h * 64 + l15 * 4;
        f32x2 xa = *(const f32x2*)xr;
        f32x2 xc = *(const f32x2*)(xr + 2);
        float o0 = bf2f(u.x) + xa.x;
        float o1 = bf2f(u.y) + xa.y;
        float o2 = bf2f(u.z) + xc.x;
        float o3 = bf2f(u.w) + xc.y;
        float* orow = out + ((size_t)(b * 256 + row)) * 514 + h * 64 + l15 * 4;
        f32x2 w0; w0.x = o0; w0.y = o1;
        f32x2 w1; w1.x = o2; w1.y = o3;
        *(f32x2*)orow = w0;
        *(f32x2*)(orow + 2) = w1;
        ushort4 xo;
        xo.x = f2bf(o0); xo.y = f2bf(o1); xo.z = f2bf(o2); xo.w = f2bf(o3);
        *(ushort4*)(Xb + ((size_t)(b * 256 + row)) * 512 + h * 64 + l15 * 4) = xo;
    }
}

// ---------------------------------------------------------------------------
// 8-phase 256x256 GEMM (BK=64, 512 threads / 8 waves, counted vmcnt).
// Wave = 32 rows x 256 cols. Phase q of tile t: ds_read quadrant (n-quarter q),
// stage one half-tile of t+1, counted vmcnt (ph1:4, ph3:2), barrier, 16 MFMA,
// barrier. LDS 128KB: A dbuf 2x32KB + B dbuf 2x32KB.
// ---------------------------------------------------------------------------
DEV void stage_half(const unsigned short* g, size_t gstride, int row0, int k0,
                    char* half_base, int w, int lane) {
    const int slot = lane & 7;
    const int r8 = lane >> 3;
    const int swz = (slot ^ r8) * 16;
    #pragma unroll
    for (int i = 0; i < 2; ++i) {
        int chunk = w * 2 + i;  // 0..15 within half
        int row = chunk * 8 + r8;
        const char* src = (const char*)(g + (size_t)(row0 + row) * gstride + k0) + swz;
        __builtin_amdgcn_global_load_lds((const glb_u32*)src,
                                         (lds_u32*)(half_base + chunk * 1024), 16, 0, 0);
    }
}

DEV void gemm8_loop(const unsigned short* A, size_t sA,
                    const unsigned short* B, size_t sB,
                    int m0, int n0, int NT,
                    char* A0, char* A1, char* B0, char* B1,
                    int w, int lane, int l15, int l4,
                    f32x4 (&acc)[2][16]) {
    // prologue: stage tile 0, counted wait
    stage_half(A, sA, m0, 0, A0, w, lane);
    stage_half(A, sA, m0 + 128, 0, A0 + 16384, w, lane);
    stage_half(B, sB, n0, 0, B0, w, lane);
    stage_half(B, sB, n0 + 128, 0, B0 + 16384, w, lane);
    asm volatile("s_waitcnt vmcnt(2)" ::: "memory");
    __builtin_amdgcn_s_barrier();
    __builtin_amdgcn_sched_barrier(0);

    for (int t = 0; t < NT; ++t) {
        const char* Ac = (t & 1) ? A1 : A0;
        const char* Bc = (t & 1) ? B1 : B0;
        char* An = (t & 1) ? A0 : A1;
        char* Bn = (t & 1) ? B0 : B1;
        const int kn = (t + 1) * 64;
        const bool more = (t + 1 < NT);
        const bool last = (t == NT - 1);
        #pragma unroll
        for (int q = 0; q < 4; ++q) {
            // ---- ds_read quadrant fragments ----
            bf16x8 af[2][2], bf[2][4];
            #pragma unroll
            for (int kk = 0; kk < 2; ++kk) {
                #pragma unroll
                for (int mt = 0; mt < 2; ++mt) {
                    int row = w * 32 + mt * 16 + l15;
                    af[kk][mt] = *(const bf16x8*)(Ac + row * 128 + ((kk * 64 + l4 * 16) ^ ((row & 7) << 4)));
                }
                #pragma unroll
                for (int nt = 0; nt < 4; ++nt) {
                    int row = q * 64 + nt * 16 + l15;
                    bf[kk][nt] = *(const bf16x8*)(Bc + row * 128 + ((kk * 64 + l4 * 16) ^ ((row & 7) << 4)));
                }
            }
            // ---- stage one half-tile of tile t+1 ----
            if (more) {
                if (q == 0) stage_half(A, sA, m0, kn, An, w, lane);
                if (q == 1) stage_half(A, sA, m0 + 128, kn, An + 16384, w, lane);
                if (q == 2) stage_half(B, sB, n0, kn, Bn, w, lane);
                if (q == 3) stage_half(B, sB, n0 + 128, kn, Bn + 16384, w, lane);
            }
            // ---- counted waits (ledger-derived) ----
            if (q == 1) {
                if (last) asm volatile("s_waitcnt vmcnt(0)" ::: "memory");
                else      asm volatile("s_waitcnt vmcnt(4)" ::: "memory");
            }
            if (q == 3) asm volatile("s_waitcnt vmcnt(2)" ::: "memory");
            __builtin_amdgcn_s_barrier();
            __builtin_amdgcn_sched_barrier(0);
            __builtin_amdgcn_s_setprio(1);
            #pragma unroll
            for (int kk = 0; kk < 2; ++kk)
                #pragma unroll
                for (int mt = 0; mt < 2; ++mt)
                    #pragma unroll
                    for (int nt = 0; nt < 4; ++nt)
                        acc[mt][q * 4 + nt] = __builtin_amdgcn_mfma_f32_16x16x32_bf16(
                            af[kk][mt], bf[kk][nt], acc[mt][q * 4 + nt], 0, 0, 0);
            __builtin_amdgcn_s_setprio(0);
            __builtin_amdgcn_sched_barrier(0);
            __builtin_amdgcn_s_barrier();
        }
    }
}

// GEMM1: G = gelu(Xb @ FW1b^T + Fb1 + sc0*w512 + sc1*w513)
__global__ __launch_bounds__(512, 1) void gemm1_kernel(
    const unsigned short* __restrict__ A,
    const unsigned short* __restrict__ B,
    const float* __restrict__ Fb1,
    const float* __restrict__ FW1,
    const float* __restrict__ scbuf,
    long pass_m0,
    unsigned short* __restrict__ G) {
    __shared__ __attribute__((aligned(16))) char smem[131072];

    const int nwg = gridDim.x;
    const int cpx = nwg >> 3;
    const int bid = (blockIdx.x & 7) * cpx + (blockIdx.x >> 3);
    const int m0 = (bid >> 3) * 256;
    const int n0 = (bid & 7) * 256;
    const int tid = threadIdx.x;
    const int lane = tid & 63;
    const int w = tid >> 6;
    const int l15 = lane & 15;
    const int l4 = lane >> 4;

    f32x4 acc[2][16];
    #pragma unroll
    for (int mt = 0; mt < 2; ++mt)
        #pragma unroll
        for (int nt = 0; nt < 16; ++nt) acc[mt][nt] = 0.f;

    gemm8_loop(A, 512, B, 512, m0, n0, 8,
               smem, smem + 32768, smem + 65536, smem + 98304,
               w, lane, l15, l4, acc);

    f32x2 scp[2][4];
    #pragma unroll
    for (int mt = 0; mt < 2; ++mt)
        #pragma unroll
        for (int r = 0; r < 4; ++r) {
            long rowg = pass_m0 + m0 + w * 32 + mt * 16 + l4 * 4 + r;
            scp[mt][r] = *(const f32x2*)(scbuf + rowg * 2);
        }
    #pragma unroll
    for (int ntg = 0; ntg < 16; ++ntg) {
        int n = n0 + ntg * 16 + l15;
        float fb = Fb1[n];
        float w512 = FW1[(size_t)n * 514 + 512];
        float w513 = FW1[(size_t)n * 514 + 513];
        #pragma unroll
        for (int mt = 0; mt < 2; ++mt)
            #pragma unroll
            for (int r = 0; r < 4; ++r) {
                long row = m0 + w * 32 + mt * 16 + l4 * 4 + r;  // pass-local
                float v = acc[mt][ntg][r] + fb + scp[mt][r].x * w512 + scp[mt][r].y * w513;
                G[row * 2048 + n] = f2bf(gelu_fast(v));
            }
    }
}

// GEMM2: io[., 0..511] += G @ FW2b^T + Fb2
__global__ __launch_bounds__(512, 1) void gemm2_kernel(
    const unsigned short* __restrict__ A,
    const unsigned short* __restrict__ B,
    const float* __restrict__ Fb2,
    long pass_m0,
    float* __restrict__ io) {
    __shared__ __attribute__((aligned(16))) char smem[131072];

    const int nwg = gridDim.x;
    const int cpx = nwg >> 3;
    const int bid = (blockIdx.x & 7) * cpx + (blockIdx.x >> 3);
    const int m0 = (bid >> 1) * 256;
    const int n0 = (bid & 1) * 256;
    const int tid = threadIdx.x;
    const int lane = tid & 63;
    const int w = tid >> 6;
    const int l15 = lane & 15;
    const int l4 = lane >> 4;

    f32x4 acc[2][16];
    #pragma unroll
    for (int mt = 0; mt < 2; ++mt)
        #pragma unroll
        for (int nt = 0; nt < 16; ++nt) acc[mt][nt] = 0.f;

    gemm8_loop(A, 2048, B, 2048, m0, n0, 32,
               smem, smem + 32768, smem + 65536, smem + 98304,
               w, lane, l15, l4, acc);

    #pragma unroll
    for (int ntg = 0; ntg < 16; ++ntg) {
        int n = n0 + ntg * 16 + l15;
        float fb = Fb2[n];
        #pragma unroll
        for (int mt = 0; mt < 2; ++mt)
            #pragma unroll
            for (int r = 0; r < 4; ++r) {
                long rowg = pass_m0 + m0 + w * 32 + mt * 16 + l4 * 4 + r;
                float* p = io + rowg * 514 + n;
                *p = acc[mt][ntg][r] + fb + *p;
            }
    }
}

// ---------------------------------------------------------------------------
extern "C" void kernel_launch(void* const* d_in, const int* in_sizes, int n_in,
                              void* d_out, int out_size, void* d_ws, size_t ws_size,
                              hipStream_t stream) {
    const float* x = (const float*)d_in[0];
    const float* Ws = (const float*)d_in[1];
    const float* bs = (const float*)d_in[2];
    const float* LW1 = (const float*)d_in[3];
    const float* Lb1 = (const float*)d_in[4];
    const float* LW2 = (const float*)d_in[5];
    const float* Lb2 = (const float*)d_in[6];
    const float* HW1 = (const float*)d_in[7];
    const float* Hb1 = (const float*)d_in[8];
    const float* HW2 = (const float*)d_in[9];
    const float* Hb2 = (const float*)d_in[10];
    const float* FW1 = (const float*)d_in[11];
    const float* Fb1 = (const float*)d_in[12];
    const float* FW2 = (const float*)d_in[13];
    const float* Fb2 = (const float*)d_in[14];
    float* out = (float*)d_out;

    char* ws = (char*)d_ws;
    unsigned short* Wsb = (unsigned short*)(ws);                 // 131072 B
    unsigned short* HW1b = (unsigned short*)(ws + 131072);       // 1048576 B
    unsigned short* HW2b = (unsigned short*)(ws + 1179648);      // 1048576 B
    unsigned short* FW1b = (unsigned short*)(ws + 2228224);      // 2097152 B
    unsigned short* FW2b = (unsigned short*)(ws + 4325376);      // 2097152 B
    float* gb = (float*)(ws + 6422528);                          // 524288 B
    float* scbuf = (float*)(ws + 6946816);                       // 524288 B
    unsigned short* Xb = (unsigned short*)(ws + 7471104);        // 67108864 B
    unsigned short* Gbuf = (unsigned short*)(ws + 7471104 + 67108864);

    const size_t fixed = 7471104 + 67108864;
    int npass = 32;
    for (int np = 1; np <= 32; np *= 2) {
        if (fixed + (size_t)268435456 / np <= ws_size) { npass = np; break; }
    }
    const long Mtot = 65536;
    const long Mp = Mtot / npass;

    cast_bf16_kernel<<<256, 256, 0, stream>>>(Ws, Wsb, 65536);
    cast_bf16_kernel<<<2048, 256, 0, stream>>>(HW1, HW1b, 524288);
    cast_bf16_kernel<<<2048, 256, 0, stream>>>(HW2, HW2b, 524288);
    cast_bf16_kernel<<<4096, 256, 0, stream>>>(FW2, FW2b, 1048576);
    cast_fw1_kernel<<<4096, 256, 0, stream>>>(FW1, FW1b);
    gb_kernel<<<32, 256, 0, stream>>>(x, LW1, Lb1, LW2, Lb2, gb);
    sc_copy_kernel<<<256, 256, 0, stream>>>(x, out, scbuf);

    mixer_kernel<<<2048, 256, 0, stream>>>(x, bs, Hb1, Hb2, Wsb, HW1b, HW2b, gb, out, Xb);

    for (int p = 0; p < npass; ++p) {
        long m0 = (long)p * Mp;
        gemm1_kernel<<<(int)(Mp / 256) * 8, 512, 0, stream>>>(
            Xb + m0 * 512, FW1b, Fb1, FW1, scbuf, m0, Gbuf);
        gemm2_kernel<<<(int)(Mp / 256) * 2, 512, 0, stream>>>(
            Gbuf, FW2b, Fb2, m0, out);
    }
}